// Round 7
// baseline (820.079 us; speedup 1.0000x reference)
//
#include <hip/hip_runtime.h>
#include <hip/hip_bf16.h>

// QuantLinear: out[m][n] = (sum_k in[m][k]*(q[n][k]-128)) * scale[n] + bias[n]
// M=512, K=4096, N=11008. A fp32, Q int32 (0..255), out fp32.
//
// R7: PRODUCER/CONSUMER fused kernel. R3-R5 showed the compiler defeats
// source-level load/compute interleaving within a wave; R6's fix (separate
// cvtQ pass) cost ~50us of pure HBM traffic to avoid a conversion whose
// chip-wide VALU cost is ~1.4us. This round: 8-wave blocks, waves 0-3 are
// pure consumers (LDS->MFMA, R6's proven compute), waves 4-7 are producers
// (global->regs->convert->ds_write). Producers are INTENTIONALLY serial;
// their vmcnt stalls overlap consumer MFMA across waves - nothing for the
// scheduler to break. One lgkmcnt-only barrier per K-step (global loads
// never drained). Padded LDS (LDP=40) kills bank conflicts on both sides;
// no swizzle needed since staging is via plain ds_write.

#define BM 64
#define BN 128
#define BK 32
#define LDP 40   // padded row: 80 B = 20 words; 20r%32 has period 8 -> 2-way max (free)

typedef __attribute__((ext_vector_type(8))) short bf16x8;
typedef __attribute__((ext_vector_type(8))) unsigned short u16x8;
typedef __attribute__((ext_vector_type(4))) unsigned short u16x4;
typedef __attribute__((ext_vector_type(4))) float f32x4;
typedef __attribute__((ext_vector_type(4))) int   i32x4;

__device__ __forceinline__ unsigned short f2bf(float x) {
  __hip_bfloat16 h = __float2bfloat16(x);
  return *reinterpret_cast<unsigned short*>(&h);
}

// ---------------- P1: A fp32 -> bf16 (12 MB traffic, ~3us) ----------------
__global__ __launch_bounds__(256)
void cvtA_kernel(const float* __restrict__ A, unsigned short* __restrict__ Abf,
                 int nquad) {
  const int stride = gridDim.x * 256;
  for (int i = blockIdx.x * 256 + threadIdx.x; i < nquad; i += stride) {
    f32x4 v = *reinterpret_cast<const f32x4*>(A + (size_t)i * 4);
    u16x4 h;
    h[0] = f2bf(v[0]); h[1] = f2bf(v[1]); h[2] = f2bf(v[2]); h[3] = f2bf(v[3]);
    *reinterpret_cast<u16x4*>(Abf + (size_t)i * 4) = h;
  }
}

// ---------------- fused producer/consumer GEMM ----------------
__global__ __launch_bounds__(512, 4)
void qfused_kernel(const unsigned short* __restrict__ Abf, // [M][K] bf16
                   const int*   __restrict__ Q,            // [N][K] int32
                   const float* __restrict__ scale,        // [N]
                   const float* __restrict__ bias,         // [N]
                   float* __restrict__ C,                  // [M][N]
                   int M, int N, int K)
{
  __shared__ unsigned short sA[2][BM][LDP];   // 2 x 64 x 40 x 2B = 10 KB
  __shared__ unsigned short sB[2][BN][LDP];   // 2 x 128 x 40 x 2B = 20 KB

  const int tid  = threadIdx.x;
  const int lane = tid & 63;
  const int wid  = tid >> 6;          // 0..7
  const bool isProd = (wid >= 4);

  const int nbm = M / BM;             // 8
  const int nwg = gridDim.x;          // 688 (div by 8)
  int wgid = blockIdx.x;
  if ((nwg & 7) == 0) wgid = (wgid & 7) * (nwg >> 3) + (wgid >> 3);
  const int bm   = wgid % nbm;
  const int bn   = wgid / nbm;
  const int row0 = bm * BM;
  const int col0 = bn * BN;

  // ---- consumer geometry (waves 0-3 as 2x2; wave-tile 32x64) ----
  const int wr = (wid >> 1) & 1;
  const int wc = wid & 1;
  const int cl = lane & 15;
  const int kb = (lane >> 4) << 3;    // k-group elem base: 0,8,16,24

  // ---- producer geometry (waves 4-7; 256 lanes total) ----
  // A tile 64x32 bf16: 256 u16x8-units: row = pl>>2, slot = pl&3
  // B tile 128x32 i32: 1024 i32x4-units: u = pl + 256*i, row = u>>3, q4 = u&7
  const int pl = (wid - 4) * 64 + lane;   // 0..255 (valid when isProd)
  const int parow = pl >> 2;              // 0..63
  const int pacol = (pl & 3) << 3;        // 0,8,16,24

  f32x4 acc[2][4];
#pragma unroll
  for (int i = 0; i < 2; ++i)
#pragma unroll
    for (int j = 0; j < 4; ++j) acc[i][j] = (f32x4)0.0f;

#define STAGE(kt_, b_) do {                                                  \
    const int _kt = (kt_);                                                   \
    u16x8 va = *(const u16x8*)(Abf + (size_t)(row0 + parow) * K + _kt + pacol); \
    *(u16x8*)&sA[b_][parow][pacol] = va;                                     \
    _Pragma("unroll")                                                        \
    for (int i = 0; i < 4; ++i) {                                            \
      const int u  = pl + (i << 8);                                          \
      const int r  = u >> 3;                                                 \
      const int q4 = (u & 7) << 2;                                           \
      i32x4 v = *(const i32x4*)(Q + (size_t)(col0 + r) * K + _kt + q4);      \
      u16x4 h;                                                               \
      h[0] = f2bf((float)(v[0] - 128));                                      \
      h[1] = f2bf((float)(v[1] - 128));                                      \
      h[2] = f2bf((float)(v[2] - 128));                                      \
      h[3] = f2bf((float)(v[3] - 128));                                      \
      *(u16x4*)&sB[b_][r][q4] = h;                                           \
    }                                                                        \
  } while (0)

#define COMPUTE(b_) do {                                                     \
    bf16x8 af0 = *(const bf16x8*)&sA[b_][wr * 32 +  0 + cl][kb];             \
    bf16x8 af1 = *(const bf16x8*)&sA[b_][wr * 32 + 16 + cl][kb];             \
    bf16x8 bv0 = *(const bf16x8*)&sB[b_][wc * 64 +  0 + cl][kb];             \
    bf16x8 bv1 = *(const bf16x8*)&sB[b_][wc * 64 + 16 + cl][kb];             \
    bf16x8 bv2 = *(const bf16x8*)&sB[b_][wc * 64 + 32 + cl][kb];             \
    bf16x8 bv3 = *(const bf16x8*)&sB[b_][wc * 64 + 48 + cl][kb];             \
    acc[0][0] = __builtin_amdgcn_mfma_f32_16x16x32_bf16(af0, bv0, acc[0][0], 0,0,0); \
    acc[0][1] = __builtin_amdgcn_mfma_f32_16x16x32_bf16(af0, bv1, acc[0][1], 0,0,0); \
    acc[0][2] = __builtin_amdgcn_mfma_f32_16x16x32_bf16(af0, bv2, acc[0][2], 0,0,0); \
    acc[0][3] = __builtin_amdgcn_mfma_f32_16x16x32_bf16(af0, bv3, acc[0][3], 0,0,0); \
    acc[1][0] = __builtin_amdgcn_mfma_f32_16x16x32_bf16(af1, bv0, acc[1][0], 0,0,0); \
    acc[1][1] = __builtin_amdgcn_mfma_f32_16x16x32_bf16(af1, bv1, acc[1][1], 0,0,0); \
    acc[1][2] = __builtin_amdgcn_mfma_f32_16x16x32_bf16(af1, bv2, acc[1][2], 0,0,0); \
    acc[1][3] = __builtin_amdgcn_mfma_f32_16x16x32_bf16(af1, bv3, acc[1][3], 0,0,0); \
  } while (0)

#define BARX() do {                                                          \
    asm volatile("s_waitcnt lgkmcnt(0)" ::: "memory");                       \
    __builtin_amdgcn_s_barrier();                                            \
  } while (0)

  const int NT = K / BK;              // 128

  if (isProd) STAGE(0, 0);
  BARX();

#pragma unroll 1
  for (int t = 0; t < NT; ++t) {
    const int cur = t & 1;
    if (isProd) {
      if (t + 1 < NT) STAGE((t + 1) * BK, cur ^ 1);
    } else {
      COMPUTE(cur);
    }
    BARX();
  }

  if (!isProd) {
    // epilogue: D col = lane&15 (n), row = (lane>>4)*4 + reg (m)  [m89/m91]
    const int rb = row0 + wr * 32 + ((lane >> 4) << 2);
#pragma unroll
    for (int ni = 0; ni < 4; ++ni) {
      const int n = col0 + wc * 64 + ni * 16 + cl;
      const float s = scale[n];
      const float b = bias[n];
#pragma unroll
      for (int mi = 0; mi < 2; ++mi) {
#pragma unroll
        for (int r = 0; r < 4; ++r) {
          C[(size_t)(rb + mi * 16 + r) * N + n] = acc[mi][ni][r] * s + b;
        }
      }
    }
  }
#undef STAGE
#undef COMPUTE
#undef BARX
}

extern "C" void kernel_launch(void* const* d_in, const int* in_sizes, int n_in,
                              void* d_out, int out_size, void* d_ws, size_t ws_size,
                              hipStream_t stream) {
  const float* inp   = (const float*)d_in[0];
  const int*   qw    = (const int*)d_in[1];
  const float* scale = (const float*)d_in[2];
  const float* bias  = (const float*)d_in[3];
  float*       out   = (float*)d_out;

  const int OUT = in_sizes[3];            // 11008
  const int IN  = in_sizes[1] / OUT;      // 4096
  const int M   = in_sizes[0] / IN;       // 512

  // ws layout: Abf (M*IN bf16 = 4.2 MB). ws_size proven ~720 MB by harness
  // poison fills (R6 profile: WRITE_SIZE 704 MB).
  unsigned short* Abf = (unsigned short*)d_ws;

  cvtA_kernel<<<1024, 256, 0, stream>>>(inp, Abf, (M * IN) >> 2);

  const int grid = (M / BM) * (OUT / BN); // 8 * 86 = 688
  qfused_kernel<<<grid, 512, 0, stream>>>(Abf, qw, scale, bias, out, M, OUT, IN);
}